// Round 12
// baseline (531.690 us; speedup 1.0000x reference)
//
#include <hip/hip_runtime.h>
#include <cstdint>

#define N_NODES 50000
#define N_EDGES 1600000
#define NH 4
#define CC 32
#define HC 128          // NH*CC
#define LAT 32
#define NEG_SLOPE 0.2f

// k_pre role split
#define NB_XP   12500                   // N_NODES*64/256
#define NB_NODE 196                     // ceil(N_NODES/256)
#define NB_PRE  (NB_XP + NB_NODE + 1)

// atomic-free degree histogram: 250 blocks x 6400-edge chunks
#define NB_H 250
#define CH_E 6400                        // 250*6400 = N_EDGES exactly

// scatter: 4 edges/thread -> 1024 edges/block
#define SC_NB ((N_EDGES + 1023) / 1024)  // 1563 (last block partial)

// ---------------- bf16 helpers (RNE pack, shift-unpack) ----------------
__device__ __forceinline__ float bflo(uint32_t u) {
    union { uint32_t i; float f; } c; c.i = u << 16; return c.f;
}
__device__ __forceinline__ float bfhi(uint32_t u) {
    union { uint32_t i; float f; } c; c.i = u & 0xFFFF0000u; return c.f;
}
__device__ __forceinline__ uint32_t f2bf(float f) {
    union { float f; uint32_t i; } c; c.f = f;
    return (c.i + 0x7FFFu + ((c.i >> 16) & 1u)) >> 16;
}
__device__ __forceinline__ uint32_t pack2(float a, float b) {
    return f2bf(a) | (f2bf(b) << 16);
}
__device__ __forceinline__ float bpermf(int byteIdx, float v) {
    return __int_as_float(__builtin_amdgcn_ds_bpermute(byteIdx, __float_as_int(v)));
}

// ---------------------------------------------------------------- kernels

// fused front end: [xp | node | v] by blockIdx range
__global__ __launch_bounds__(256) void k_pre(const float* __restrict__ x,
                                             const float* __restrict__ W_gat,
                                             const float* __restrict__ att_src,
                                             const float* __restrict__ att_dst,
                                             const float* __restrict__ W_edge,
                                             const float* __restrict__ att_edge,
                                             uint32_t* __restrict__ xp2,
                                             float4* __restrict__ a_src,
                                             float4* __restrict__ a_dst,
                                             float* __restrict__ v) {
    int bid = blockIdx.x, t = threadIdx.x;
    if (bid < NB_XP) {
        int k = bid * 256 + t;
        int n = k >> 6, c = (k & 63) * 2;
        float x0 = x[n * 3 + 0], x1 = x[n * 3 + 1], x2 = x[n * 3 + 2];
        float a = x0 * W_gat[c]   + x1 * W_gat[128 + c]   + x2 * W_gat[256 + c];
        float b = x0 * W_gat[c+1] + x1 * W_gat[128 + c+1] + x2 * W_gat[256 + c+1];
        xp2[k] = pack2(a, b);
    } else if (bid < NB_XP + NB_NODE) {
        __shared__ float us[12], ud[12];
        if (t < 12) {
            int i = t >> 2, h = t & 3;
            float s = 0.f;
            #pragma unroll
            for (int c = 0; c < 32; ++c)
                s += W_gat[i * 128 + h * 32 + c] * att_src[h * 32 + c];
            us[t] = s;
        } else if (t < 24) {
            int q = t - 12; int i = q >> 2, h = q & 3;
            float s = 0.f;
            #pragma unroll
            for (int c = 0; c < 32; ++c)
                s += W_gat[i * 128 + h * 32 + c] * att_dst[h * 32 + c];
            ud[q] = s;
        }
        __syncthreads();
        int n = (bid - NB_XP) * 256 + t;
        if (n < N_NODES) {
            float x0 = x[n * 3 + 0], x1 = x[n * 3 + 1], x2 = x[n * 3 + 2];
            float s[4], d[4];
            #pragma unroll
            for (int h = 0; h < 4; ++h) {
                s[h] = x0 * us[h] + x1 * us[4 + h] + x2 * us[8 + h];
                d[h] = x0 * ud[h] + x1 * ud[4 + h] + x2 * ud[8 + h];
            }
            a_src[n] = make_float4(s[0], s[1], s[2], s[3]);
            a_dst[n] = make_float4(d[0], d[1], d[2], d[3]);
        }
    } else {
        if (t < 28) {
            int d = t >> 2, h = t & 3;
            float s = 0.f;
            #pragma unroll
            for (int c = 0; c < 32; ++c)
                s += W_edge[d * 128 + h * 32 + c] * att_edge[h * 32 + c];
            v[t] = s;
        }
    }
}

// atomic-free degree count: per-block privatized LDS histogram (uint16 pairs
// packed in uint32; no carry since per-chunk counts << 2^16).
__global__ __launch_bounds__(256) void k_hist(const int* __restrict__ ei,
                                              uint16_t* __restrict__ hist) {
    __shared__ uint32_t lh[12500];             // 25000 uint16 bins per pass
    int t = threadIdx.x, b = blockIdx.x;
    int base = b * CH_E;
    uint32_t* orow = (uint32_t*)(hist + (size_t)b * N_NODES);
    #pragma unroll 1
    for (int p = 0; p < 2; ++p) {
        for (int i = t; i < 12500; i += 256) lh[i] = 0;
        __syncthreads();
        int lo = p * 25000;
        #pragma unroll 1
        for (int it = 0; it < CH_E / 256; ++it) {
            int dst = ei[N_EDGES + base + it * 256 + t];
            int r = dst - lo;
            if (r >= 0 && r < 25000)
                atomicAdd(&lh[r >> 1], 1u << ((r & 1) * 16));
        }
        __syncthreads();
        for (int i = t; i < 12500; i += 256)
            orow[p * 12500 + i] = lh[i];       // coalesced packed store
        __syncthreads();
    }
}

// sum the 250 partial histograms per node -> cnt
__global__ __launch_bounds__(256) void k_red(const uint16_t* __restrict__ hist,
                                             int* __restrict__ cnt) {
    int i = blockIdx.x * 256 + threadIdx.x;
    if (i >= N_NODES) return;
    int run = 0;
    size_t off = i;
    #pragma unroll 1
    for (int b = 0; b < NB_H; ++b, off += N_NODES)
        run += hist[off];
    cnt[i] = run;
}

// single-block exclusive prefix sum over cnt -> rowptr[N+1]
__global__ __launch_bounds__(1024) void k_scan(const int* __restrict__ cnt,
                                               int* __restrict__ rowptr) {
    __shared__ int part[1024];
    int t = threadIdx.x;
    const int W = (N_NODES + 1023) / 1024;
    int lo = t * W, hi = min(lo + W, N_NODES);
    int s = 0;
    for (int i = lo; i < hi; ++i) s += cnt[i];
    part[t] = s;
    __syncthreads();
    for (int off = 1; off < 1024; off <<= 1) {
        int vv = (t >= off) ? part[t - off] : 0;
        __syncthreads();
        part[t] += vv;
        __syncthreads();
    }
    int run = part[t] - s;   // exclusive base
    for (int i = lo; i < hi; ++i) { rowptr[i] = run; run += cnt[i]; }
    if (t == 1023) rowptr[N_NODES] = part[1023];
}

// 4 edges/thread scatter (1024 edges/block): R11 showed one dependent
// chain (atomicSub -> addr -> store) per thread with no other work =
// latency-bound (VALU 3%, HBM 18%, occ 67%). Four independent chains per
// thread: batched ei loads, rowptr prefetched BEFORE the atomics, 4 atomics
// in flight, then 4 stores. Slot claimed by DECREMENTING cnt.
__global__ __launch_bounds__(256) void k_scatter(const int* __restrict__ ei,
                                                 const float* __restrict__ edge_attr,
                                                 const float* __restrict__ v,
                                                 const int* __restrict__ rowptr,
                                                 int* __restrict__ cnt,
                                                 uint4* __restrict__ csr) {
    __shared__ float vs[28];
    __shared__ float ea_s[1024 * 7];           // 28KB
    int t = threadIdx.x;
    if (t < 28) vs[t] = v[t];
    int e0 = blockIdx.x * 1024;
    #pragma unroll
    for (int i = 0; i < 28; ++i) {
        int idx = e0 * 7 + t + i * 256;
        if (idx < N_EDGES * 7) ea_s[t + i * 256] = edge_attr[idx];
    }
    __syncthreads();

    bool ok[4];
    int dst[4], rp[4], srcv[4];
    #pragma unroll
    for (int q = 0; q < 4; ++q) {
        int e = e0 + q * 256 + t;
        ok[q] = e < N_EDGES;
        int ec = ok[q] ? e : (N_EDGES - 1);
        srcv[q] = ei[ec];
        dst[q]  = ei[N_EDGES + ec];
    }
    #pragma unroll
    for (int q = 0; q < 4; ++q)
        rp[q] = rowptr[dst[q]];                // independent of atomics: overlap

    uint4 rec[4];
    #pragma unroll
    for (int q = 0; q < 4; ++q) {
        int le = q * 256 + t;
        float ea[7];
        #pragma unroll
        for (int d = 0; d < 7; ++d) ea[d] = ea_s[le * 7 + d];
        float aeo[4];
        #pragma unroll
        for (int h = 0; h < 4; ++h) {
            float aeh = 0.f;
            #pragma unroll
            for (int d = 0; d < 7; ++d) aeh += ea[d] * vs[d * 4 + h];
            aeo[h] = aeh;
        }
        rec[q] = make_uint4(pack2(aeo[0], aeo[1]), pack2(aeo[2], aeo[3]),
                            (uint32_t)srcv[q], 0u);
    }

    int c[4];
    #pragma unroll
    for (int q = 0; q < 4; ++q)
        if (ok[q]) c[q] = atomicSub(&cnt[dst[q]], 1);   // 4 atomics in flight
    #pragma unroll
    for (int q = 0; q < 4; ++q)
        if (ok[q]) csr[rp[q] + c[q] - 1] = rec[q];
}

// 2 nodes per 128-thr block (one wave each), 2 channels/lane.
// Batch-16 lane-distributed scheme (R7 form).
__global__ __launch_bounds__(128) void k_gather(const int* __restrict__ rowptr,
                                                const uint4* __restrict__ csr,
                                                const uint32_t* __restrict__ xp2,
                                                const float* __restrict__ a_src,
                                                const float* __restrict__ a_dst,
                                                const float* __restrict__ bias_gat,
                                                float2* __restrict__ h_buf) {
    int n = blockIdx.x * 2 + (threadIdx.x >> 6);
    int l = threadIdx.x & 63;     // lane 0..63; channels 2l, 2l+1
    int h = l >> 4;               // head
    int i16 = l & 15;             // edge slot within a 16-batch
    int hb = h * 64;              // bpermute byte base: lanes [h*16, h*16+16)
    int start = rowptr[n], end = rowptr[n + 1];
    int deg = end - start;

    float ad_n = a_dst[n * 4 + h];
    float as_n = a_src[n * 4 + h];

    float acc0 = 0.f, acc1 = 0.f, den = 0.f;
    float aeb = 0.f, aer = 0.f;

    int nb = deg >> 4;
    int p = start;
    for (int b = 0; b < nb; ++b, p += 16) {
        uint4 rec = csr[p + i16];          // 16 consecutive recs, coalesced
        uint32_t aw = (h < 2) ? rec.x : rec.y;
        float ae = (h & 1) ? bfhi(aw) : bflo(aw);
        int srcv = (int)rec.z;
        float al = ae + a_src[srcv * 4 + h] + ad_n;
        al = al > 0.f ? al : NEG_SLOPE * al;
        float w = __expf(al);              // one exp covers 16 edges
        aeb += ae;
        #pragma unroll
        for (int i = 0; i < 16; ++i) {
            int s = __builtin_amdgcn_readlane(srcv, i);       // SGPR src
            float wi = bpermf(hb + i * 4, w);                 // my head's w_i
            uint32_t xu = xp2[s * 64 + l];                    // coalesced 256B
            acc0 += wi * bflo(xu);
            acc1 += wi * bfhi(xu);
            den  += wi;
        }
    }
    // remainder: scalar path (all lanes, one edge at a time)
    for (; p < end; ++p) {
        uint4 rec = csr[p];
        uint32_t aw = (h < 2) ? rec.x : rec.y;
        float ae = (h & 1) ? bfhi(aw) : bflo(aw);
        int src = (int)rec.z;
        float al = ae + a_src[src * 4 + h] + ad_n;
        al = al > 0.f ? al : NEG_SLOPE * al;
        float w = __expf(al);
        uint32_t xu = xp2[src * 64 + l];
        acc0 += w * bflo(xu);
        acc1 += w * bfhi(xu);
        den  += w;
        aer  += ae;
    }

    // aesum: reduce batch partials across the 16-lane head group, + remainder
    float aesum = aeb;
    aesum += __shfl_xor(aesum, 1);
    aesum += __shfl_xor(aesum, 2);
    aesum += __shfl_xor(aesum, 4);
    aesum += __shfl_xor(aesum, 8);
    aesum += aer;

    // self loop: edge_attr = mean of incoming aeh (linearity of the .v dot)
    float invd = (deg > 0) ? (1.0f / (float)deg) : 1.0f;
    float alS = as_n + ad_n + aesum * invd;
    alS = alS > 0.f ? alS : NEG_SLOPE * alS;
    float wS = __expf(alS);
    uint32_t xs = xp2[n * 64 + l];
    acc0 += wS * bflo(xs);
    acc1 += wS * bfhi(xs);
    den  += wS;

    float2 bia = ((const float2*)bias_gat)[l];
    float r = 1.0f / den;
    float o0 = acc0 * r + bia.x;
    float o1 = acc1 * r + bia.y;
    o0 = o0 > 0.f ? o0 : (__expf(o0) - 1.0f);   // ELU
    o1 = o1 > 0.f ? o1 : (__expf(o1) - 1.0f);
    h_buf[n * 64 + l] = make_float2(o0, o1);
}

// fused MLP v2: 16 rows per 256-thread block, float4 LDS reads,
// 8 accumulators/thread.
__global__ __launch_bounds__(256) void k_mlp(const float* __restrict__ h_buf,
                                             const float* __restrict__ W1,
                                             const float* __restrict__ b1,
                                             const float* __restrict__ prelu_a,
                                             const float* __restrict__ W2,
                                             const float* __restrict__ b2,
                                             float* __restrict__ out) {
    __shared__ float sh[16][128];
    __shared__ float sh1[16][128];
    int t = threadIdx.x;
    int nb = blockIdx.x * 16;
    const float4* hb4 = (const float4*)(h_buf + (size_t)nb * 128);
    float4* sh4 = (float4*)sh;
    sh4[t]       = hb4[t];           // rows 0..7
    sh4[t + 256] = hb4[t + 256];     // rows 8..15
    __syncthreads();
    int k = t & 127, g = t >> 7;     // g in {0,1}: rows g*8..g*8+7
    float acc[8];
    float bb = b1[k];
    #pragma unroll
    for (int r = 0; r < 8; ++r) acc[r] = bb;
    const float4* shg = (const float4*)&sh[g * 8][0];   // row r at shg[r*32+d4]
    #pragma unroll 4
    for (int d4 = 0; d4 < 32; ++d4) {
        float w0 = W1[(d4 * 4 + 0) * 128 + k];
        float w1 = W1[(d4 * 4 + 1) * 128 + k];
        float w2 = W1[(d4 * 4 + 2) * 128 + k];
        float w3 = W1[(d4 * 4 + 3) * 128 + k];
        #pragma unroll
        for (int r = 0; r < 8; ++r) {
            float4 hv = shg[r * 32 + d4];
            acc[r] += hv.x * w0 + hv.y * w1 + hv.z * w2 + hv.w * w3;
        }
    }
    float a = prelu_a[0];
    #pragma unroll
    for (int r = 0; r < 8; ++r) {
        float vv = acc[r];
        sh1[g * 8 + r][k] = vv > 0.f ? vv : a * vv;
    }
    __syncthreads();
    int j = t & 31, r2 = t >> 5;     // r2 in 0..7; handles rows r2 and r2+8
    float o0 = b2[j], o1 = b2[j];
    const float4* s1a = (const float4*)&sh1[r2][0];
    const float4* s1b = (const float4*)&sh1[r2 + 8][0];
    #pragma unroll 4
    for (int d4 = 0; d4 < 32; ++d4) {
        float w0 = W2[(d4 * 4 + 0) * 32 + j];
        float w1 = W2[(d4 * 4 + 1) * 32 + j];
        float w2 = W2[(d4 * 4 + 2) * 32 + j];
        float w3 = W2[(d4 * 4 + 3) * 32 + j];
        float4 h0 = s1a[d4], h1 = s1b[d4];
        o0 += h0.x * w0 + h0.y * w1 + h0.z * w2 + h0.w * w3;
        o1 += h1.x * w0 + h1.y * w1 + h1.z * w2 + h1.w * w3;
    }
    out[(nb + r2) * 32 + j]     = o0;
    out[(nb + r2 + 8) * 32 + j] = o1;
}

// ---------------------------------------------------------------- launch

extern "C" void kernel_launch(void* const* d_in, const int* in_sizes, int n_in,
                              void* d_out, int out_size, void* d_ws, size_t ws_size,
                              hipStream_t stream) {
    const float* x        = (const float*)d_in[0];
    const int*   ei       = (const int*)d_in[1];     // int32 per harness contract
    const float* edge_attr= (const float*)d_in[2];
    const float* W_gat    = (const float*)d_in[3];
    const float* att_src  = (const float*)d_in[4];
    const float* att_dst  = (const float*)d_in[5];
    const float* W_edge   = (const float*)d_in[6];
    const float* att_edge = (const float*)d_in[7];
    const float* bias_gat = (const float*)d_in[8];
    const float* W1       = (const float*)d_in[9];
    const float* b1       = (const float*)d_in[10];
    const float* prelu_a  = (const float*)d_in[11];
    const float* W2       = (const float*)d_in[12];
    const float* b2       = (const float*)d_in[13];
    float*       out      = (float*)d_out;

    char* base = (char*)d_ws;
    size_t off = 0;
    auto alloc = [&](size_t bytes) -> void* {
        void* p = base + off;
        off = (off + bytes + 255) & ~(size_t)255;
        return p;
    };
    int*      cnt     = (int*)     alloc((size_t)N_NODES * 4);
    int*      rowptr  = (int*)     alloc((size_t)(N_NODES + 1) * 4);
    float*    v       = (float*)   alloc(32 * 4);
    float*    a_src   = (float*)   alloc((size_t)N_NODES * 4 * 4);
    float*    a_dst   = (float*)   alloc((size_t)N_NODES * 4 * 4);
    uint32_t* xp2     = (uint32_t*)alloc((size_t)N_NODES * 64 * 4);
    uint4*    csr     = (uint4*)   alloc((size_t)N_EDGES * 16);
    float*    h_buf   = (float*)   alloc((size_t)N_NODES * 128 * 4);
    uint16_t* hist    = (uint16_t*)alloc((size_t)NB_H * N_NODES * 2);

    k_pre <<<NB_PRE, 256, 0, stream>>>(x, W_gat, att_src, att_dst,
                                       W_edge, att_edge, xp2,
                                       (float4*)a_src, (float4*)a_dst, v);
    k_hist<<<NB_H, 256, 0, stream>>>(ei, hist);
    k_red <<<196, 256, 0, stream>>>(hist, cnt);
    k_scan<<<1, 1024, 0, stream>>>(cnt, rowptr);
    k_scatter<<<SC_NB, 256, 0, stream>>>(
        ei, edge_attr, v, rowptr, cnt, csr);
    k_gather<<<N_NODES / 2, 128, 0, stream>>>(
        rowptr, csr, xp2, a_src, a_dst, bias_gat, (float2*)h_buf);
    k_mlp <<<N_NODES / 16, 256, 0, stream>>>(h_buf, W1, b1, prelu_a, W2, b2, out);
}

// Round 13
// 472.436 us; speedup vs baseline: 1.1254x; 1.1254x over previous
//
#include <hip/hip_runtime.h>
#include <cstdint>

#define N_NODES 50000
#define N_EDGES 1600000
#define NH 4
#define CC 32
#define HC 128          // NH*CC
#define LAT 32
#define NEG_SLOPE 0.2f

// k_pre role split
#define NB_XP   12500                   // N_NODES*64/256
#define NB_NODE 196                     // ceil(N_NODES/256)
#define NB_PRE  (NB_XP + NB_NODE + 1)

// atomic-free degree histogram: 250 blocks x 6400-edge chunks
#define NB_H 250
#define CH_E 6400                        // 250*6400 = N_EDGES exactly

// scatter: 4 consecutive edges/thread, no LDS; 1562 full blocks + 1 tail block
#define SC_FULL 1562                     // covers 1562*1024 = 1,599,488 edges
#define SC_TAIL (N_EDGES - SC_FULL * 1024)   // 512

// ---------------- bf16 helpers (RNE pack, shift-unpack) ----------------
__device__ __forceinline__ float bflo(uint32_t u) {
    union { uint32_t i; float f; } c; c.i = u << 16; return c.f;
}
__device__ __forceinline__ float bfhi(uint32_t u) {
    union { uint32_t i; float f; } c; c.i = u & 0xFFFF0000u; return c.f;
}
__device__ __forceinline__ uint32_t f2bf(float f) {
    union { float f; uint32_t i; } c; c.f = f;
    return (c.i + 0x7FFFu + ((c.i >> 16) & 1u)) >> 16;
}
__device__ __forceinline__ uint32_t pack2(float a, float b) {
    return f2bf(a) | (f2bf(b) << 16);
}
__device__ __forceinline__ float bpermf(int byteIdx, float v) {
    return __int_as_float(__builtin_amdgcn_ds_bpermute(byteIdx, __float_as_int(v)));
}

// ---------------------------------------------------------------- kernels

// fused front end: [xp | node | v] by blockIdx range
__global__ __launch_bounds__(256) void k_pre(const float* __restrict__ x,
                                             const float* __restrict__ W_gat,
                                             const float* __restrict__ att_src,
                                             const float* __restrict__ att_dst,
                                             const float* __restrict__ W_edge,
                                             const float* __restrict__ att_edge,
                                             uint32_t* __restrict__ xp2,
                                             float4* __restrict__ a_src,
                                             float4* __restrict__ a_dst,
                                             float* __restrict__ v) {
    int bid = blockIdx.x, t = threadIdx.x;
    if (bid < NB_XP) {
        int k = bid * 256 + t;
        int n = k >> 6, c = (k & 63) * 2;
        float x0 = x[n * 3 + 0], x1 = x[n * 3 + 1], x2 = x[n * 3 + 2];
        float a = x0 * W_gat[c]   + x1 * W_gat[128 + c]   + x2 * W_gat[256 + c];
        float b = x0 * W_gat[c+1] + x1 * W_gat[128 + c+1] + x2 * W_gat[256 + c+1];
        xp2[k] = pack2(a, b);
    } else if (bid < NB_XP + NB_NODE) {
        __shared__ float us[12], ud[12];
        if (t < 12) {
            int i = t >> 2, h = t & 3;
            float s = 0.f;
            #pragma unroll
            for (int c = 0; c < 32; ++c)
                s += W_gat[i * 128 + h * 32 + c] * att_src[h * 32 + c];
            us[t] = s;
        } else if (t < 24) {
            int q = t - 12; int i = q >> 2, h = q & 3;
            float s = 0.f;
            #pragma unroll
            for (int c = 0; c < 32; ++c)
                s += W_gat[i * 128 + h * 32 + c] * att_dst[h * 32 + c];
            ud[q] = s;
        }
        __syncthreads();
        int n = (bid - NB_XP) * 256 + t;
        if (n < N_NODES) {
            float x0 = x[n * 3 + 0], x1 = x[n * 3 + 1], x2 = x[n * 3 + 2];
            float s[4], d[4];
            #pragma unroll
            for (int h = 0; h < 4; ++h) {
                s[h] = x0 * us[h] + x1 * us[4 + h] + x2 * us[8 + h];
                d[h] = x0 * ud[h] + x1 * ud[4 + h] + x2 * ud[8 + h];
            }
            a_src[n] = make_float4(s[0], s[1], s[2], s[3]);
            a_dst[n] = make_float4(d[0], d[1], d[2], d[3]);
        }
    } else {
        if (t < 28) {
            int d = t >> 2, h = t & 3;
            float s = 0.f;
            #pragma unroll
            for (int c = 0; c < 32; ++c)
                s += W_edge[d * 128 + h * 32 + c] * att_edge[h * 32 + c];
            v[t] = s;
        }
    }
}

// atomic-free degree count: per-block privatized LDS histogram (uint16 pairs
// packed in uint32; no carry since per-chunk counts << 2^16).
__global__ __launch_bounds__(256) void k_hist(const int* __restrict__ ei,
                                              uint16_t* __restrict__ hist) {
    __shared__ uint32_t lh[12500];             // 25000 uint16 bins per pass
    int t = threadIdx.x, b = blockIdx.x;
    int base = b * CH_E;
    uint32_t* orow = (uint32_t*)(hist + (size_t)b * N_NODES);
    #pragma unroll 1
    for (int p = 0; p < 2; ++p) {
        for (int i = t; i < 12500; i += 256) lh[i] = 0;
        __syncthreads();
        int lo = p * 25000;
        #pragma unroll 1
        for (int it = 0; it < CH_E / 256; ++it) {
            int dst = ei[N_EDGES + base + it * 256 + t];
            int r = dst - lo;
            if (r >= 0 && r < 25000)
                atomicAdd(&lh[r >> 1], 1u << ((r & 1) * 16));
        }
        __syncthreads();
        for (int i = t; i < 12500; i += 256)
            orow[p * 12500 + i] = lh[i];       // coalesced packed store
        __syncthreads();
    }
}

// sum the 250 partial histograms per node -> cnt
__global__ __launch_bounds__(256) void k_red(const uint16_t* __restrict__ hist,
                                             int* __restrict__ cnt) {
    int i = blockIdx.x * 256 + threadIdx.x;
    if (i >= N_NODES) return;
    int run = 0;
    size_t off = i;
    #pragma unroll 1
    for (int b = 0; b < NB_H; ++b, off += N_NODES)
        run += hist[off];
    cnt[i] = run;
}

// single-block exclusive prefix sum over cnt -> rowptr[N+1]
__global__ __launch_bounds__(1024) void k_scan(const int* __restrict__ cnt,
                                               int* __restrict__ rowptr) {
    __shared__ int part[1024];
    int t = threadIdx.x;
    const int W = (N_NODES + 1023) / 1024;
    int lo = t * W, hi = min(lo + W, N_NODES);
    int s = 0;
    for (int i = lo; i < hi; ++i) s += cnt[i];
    part[t] = s;
    __syncthreads();
    for (int off = 1; off < 1024; off <<= 1) {
        int vv = (t >= off) ? part[t - off] : 0;
        __syncthreads();
        part[t] += vv;
        __syncthreads();
    }
    int run = part[t] - s;   // exclusive base
    for (int i = lo; i < hi; ++i) { rowptr[i] = run; run += cnt[i]; }
    if (t == 1023) rowptr[N_NODES] = part[1023];
}

// scatter v3: 4 CONSECUTIVE edges/thread, ZERO LDS (R12's 28KB LDS staging
// collapsed occupancy to 39% and regressed; this keeps the 4 independent
// atomic->store chains but with int4/float4 direct loads and scalar v reads).
// Full blocks only; tail block (blockIdx==SC_FULL) takes the last 512 edges
// via a guarded scalar path (avoids int4 OOB past ei).
__global__ __launch_bounds__(256) void k_scatter(const int* __restrict__ ei,
                                                 const float* __restrict__ edge_attr,
                                                 const float* __restrict__ v,
                                                 const int* __restrict__ rowptr,
                                                 int* __restrict__ cnt,
                                                 uint4* __restrict__ csr) {
    int t = threadIdx.x;
    float vsr[28];
    #pragma unroll
    for (int i = 0; i < 28; ++i) vsr[i] = v[i];   // uniform addr -> s_load

    if (blockIdx.x == SC_FULL) {
        // tail: 512 edges, 2 per thread, scalar guarded
        int e0 = SC_FULL * 1024;
        #pragma unroll
        for (int q = 0; q < 2; ++q) {
            int e = e0 + q * 256 + t;
            if (e >= N_EDGES) continue;
            int src = ei[e];
            int dst = ei[N_EDGES + e];
            float aeo[4];
            #pragma unroll
            for (int h = 0; h < 4; ++h) {
                float aeh = 0.f;
                #pragma unroll
                for (int d = 0; d < 7; ++d)
                    aeh += edge_attr[e * 7 + d] * vsr[d * 4 + h];
                aeo[h] = aeh;
            }
            int c = atomicSub(&cnt[dst], 1);
            csr[rowptr[dst] + c - 1] =
                make_uint4(pack2(aeo[0], aeo[1]), pack2(aeo[2], aeo[3]),
                           (uint32_t)src, 0u);
        }
        return;
    }

    int e = blockIdx.x * 1024 + t * 4;            // 4 consecutive edges
    int4 s4 = *(const int4*)&ei[e];
    int4 d4 = *(const int4*)&ei[N_EDGES + e];
    int srcv[4] = {s4.x, s4.y, s4.z, s4.w};
    int dst[4]  = {d4.x, d4.y, d4.z, d4.w};

    int rp[4];
    #pragma unroll
    for (int q = 0; q < 4; ++q)
        rp[q] = rowptr[dst[q]];                   // independent of atomics

    // 28 contiguous floats = 7 aligned float4 loads (e%4==0 -> 16B aligned)
    const float4* ea4 = (const float4*)&edge_attr[e * 7];
    float ea[28];
    #pragma unroll
    for (int i = 0; i < 7; ++i) {
        float4 vv = ea4[i];
        ea[i * 4 + 0] = vv.x; ea[i * 4 + 1] = vv.y;
        ea[i * 4 + 2] = vv.z; ea[i * 4 + 3] = vv.w;
    }

    uint4 rec[4];
    #pragma unroll
    for (int q = 0; q < 4; ++q) {
        float aeo[4];
        #pragma unroll
        for (int h = 0; h < 4; ++h) {
            float aeh = 0.f;
            #pragma unroll
            for (int d = 0; d < 7; ++d) aeh += ea[q * 7 + d] * vsr[d * 4 + h];
            aeo[h] = aeh;
        }
        rec[q] = make_uint4(pack2(aeo[0], aeo[1]), pack2(aeo[2], aeo[3]),
                            (uint32_t)srcv[q], 0u);
    }

    int c[4];
    #pragma unroll
    for (int q = 0; q < 4; ++q)
        c[q] = atomicSub(&cnt[dst[q]], 1);        // 4 atomics in flight
    #pragma unroll
    for (int q = 0; q < 4; ++q)
        csr[rp[q] + c[q] - 1] = rec[q];
}

// 2 nodes per 128-thr block (one wave each), 2 channels/lane.
// Batch-16 lane-distributed scheme (R7 form).
__global__ __launch_bounds__(128) void k_gather(const int* __restrict__ rowptr,
                                                const uint4* __restrict__ csr,
                                                const uint32_t* __restrict__ xp2,
                                                const float* __restrict__ a_src,
                                                const float* __restrict__ a_dst,
                                                const float* __restrict__ bias_gat,
                                                float2* __restrict__ h_buf) {
    int n = blockIdx.x * 2 + (threadIdx.x >> 6);
    int l = threadIdx.x & 63;     // lane 0..63; channels 2l, 2l+1
    int h = l >> 4;               // head
    int i16 = l & 15;             // edge slot within a 16-batch
    int hb = h * 64;              // bpermute byte base: lanes [h*16, h*16+16)
    int start = rowptr[n], end = rowptr[n + 1];
    int deg = end - start;

    float ad_n = a_dst[n * 4 + h];
    float as_n = a_src[n * 4 + h];

    float acc0 = 0.f, acc1 = 0.f, den = 0.f;
    float aeb = 0.f, aer = 0.f;

    int nb = deg >> 4;
    int p = start;
    for (int b = 0; b < nb; ++b, p += 16) {
        uint4 rec = csr[p + i16];          // 16 consecutive recs, coalesced
        uint32_t aw = (h < 2) ? rec.x : rec.y;
        float ae = (h & 1) ? bfhi(aw) : bflo(aw);
        int srcv = (int)rec.z;
        float al = ae + a_src[srcv * 4 + h] + ad_n;
        al = al > 0.f ? al : NEG_SLOPE * al;
        float w = __expf(al);              // one exp covers 16 edges
        aeb += ae;
        #pragma unroll
        for (int i = 0; i < 16; ++i) {
            int s = __builtin_amdgcn_readlane(srcv, i);       // SGPR src
            float wi = bpermf(hb + i * 4, w);                 // my head's w_i
            uint32_t xu = xp2[s * 64 + l];                    // coalesced 256B
            acc0 += wi * bflo(xu);
            acc1 += wi * bfhi(xu);
            den  += wi;
        }
    }
    // remainder: scalar path (all lanes, one edge at a time)
    for (; p < end; ++p) {
        uint4 rec = csr[p];
        uint32_t aw = (h < 2) ? rec.x : rec.y;
        float ae = (h & 1) ? bfhi(aw) : bflo(aw);
        int src = (int)rec.z;
        float al = ae + a_src[src * 4 + h] + ad_n;
        al = al > 0.f ? al : NEG_SLOPE * al;
        float w = __expf(al);
        uint32_t xu = xp2[src * 64 + l];
        acc0 += w * bflo(xu);
        acc1 += w * bfhi(xu);
        den  += w;
        aer  += ae;
    }

    // aesum: reduce batch partials across the 16-lane head group, + remainder
    float aesum = aeb;
    aesum += __shfl_xor(aesum, 1);
    aesum += __shfl_xor(aesum, 2);
    aesum += __shfl_xor(aesum, 4);
    aesum += __shfl_xor(aesum, 8);
    aesum += aer;

    // self loop: edge_attr = mean of incoming aeh (linearity of the .v dot)
    float invd = (deg > 0) ? (1.0f / (float)deg) : 1.0f;
    float alS = as_n + ad_n + aesum * invd;
    alS = alS > 0.f ? alS : NEG_SLOPE * alS;
    float wS = __expf(alS);
    uint32_t xs = xp2[n * 64 + l];
    acc0 += wS * bflo(xs);
    acc1 += wS * bfhi(xs);
    den  += wS;

    float2 bia = ((const float2*)bias_gat)[l];
    float r = 1.0f / den;
    float o0 = acc0 * r + bia.x;
    float o1 = acc1 * r + bia.y;
    o0 = o0 > 0.f ? o0 : (__expf(o0) - 1.0f);   // ELU
    o1 = o1 > 0.f ? o1 : (__expf(o1) - 1.0f);
    h_buf[n * 64 + l] = make_float2(o0, o1);
}

// fused MLP v2: 16 rows per 256-thread block, float4 LDS reads,
// 8 accumulators/thread.
__global__ __launch_bounds__(256) void k_mlp(const float* __restrict__ h_buf,
                                             const float* __restrict__ W1,
                                             const float* __restrict__ b1,
                                             const float* __restrict__ prelu_a,
                                             const float* __restrict__ W2,
                                             const float* __restrict__ b2,
                                             float* __restrict__ out) {
    __shared__ float sh[16][128];
    __shared__ float sh1[16][128];
    int t = threadIdx.x;
    int nb = blockIdx.x * 16;
    const float4* hb4 = (const float4*)(h_buf + (size_t)nb * 128);
    float4* sh4 = (float4*)sh;
    sh4[t]       = hb4[t];           // rows 0..7
    sh4[t + 256] = hb4[t + 256];     // rows 8..15
    __syncthreads();
    int k = t & 127, g = t >> 7;     // g in {0,1}: rows g*8..g*8+7
    float acc[8];
    float bb = b1[k];
    #pragma unroll
    for (int r = 0; r < 8; ++r) acc[r] = bb;
    const float4* shg = (const float4*)&sh[g * 8][0];   // row r at shg[r*32+d4]
    #pragma unroll 4
    for (int d4 = 0; d4 < 32; ++d4) {
        float w0 = W1[(d4 * 4 + 0) * 128 + k];
        float w1 = W1[(d4 * 4 + 1) * 128 + k];
        float w2 = W1[(d4 * 4 + 2) * 128 + k];
        float w3 = W1[(d4 * 4 + 3) * 128 + k];
        #pragma unroll
        for (int r = 0; r < 8; ++r) {
            float4 hv = shg[r * 32 + d4];
            acc[r] += hv.x * w0 + hv.y * w1 + hv.z * w2 + hv.w * w3;
        }
    }
    float a = prelu_a[0];
    #pragma unroll
    for (int r = 0; r < 8; ++r) {
        float vv = acc[r];
        sh1[g * 8 + r][k] = vv > 0.f ? vv : a * vv;
    }
    __syncthreads();
    int j = t & 31, r2 = t >> 5;     // r2 in 0..7; handles rows r2 and r2+8
    float o0 = b2[j], o1 = b2[j];
    const float4* s1a = (const float4*)&sh1[r2][0];
    const float4* s1b = (const float4*)&sh1[r2 + 8][0];
    #pragma unroll 4
    for (int d4 = 0; d4 < 32; ++d4) {
        float w0 = W2[(d4 * 4 + 0) * 32 + j];
        float w1 = W2[(d4 * 4 + 1) * 32 + j];
        float w2 = W2[(d4 * 4 + 2) * 32 + j];
        float w3 = W2[(d4 * 4 + 3) * 32 + j];
        float4 h0 = s1a[d4], h1 = s1b[d4];
        o0 += h0.x * w0 + h0.y * w1 + h0.z * w2 + h0.w * w3;
        o1 += h1.x * w0 + h1.y * w1 + h1.z * w2 + h1.w * w3;
    }
    out[(nb + r2) * 32 + j]     = o0;
    out[(nb + r2 + 8) * 32 + j] = o1;
}

// ---------------------------------------------------------------- launch

extern "C" void kernel_launch(void* const* d_in, const int* in_sizes, int n_in,
                              void* d_out, int out_size, void* d_ws, size_t ws_size,
                              hipStream_t stream) {
    const float* x        = (const float*)d_in[0];
    const int*   ei       = (const int*)d_in[1];     // int32 per harness contract
    const float* edge_attr= (const float*)d_in[2];
    const float* W_gat    = (const float*)d_in[3];
    const float* att_src  = (const float*)d_in[4];
    const float* att_dst  = (const float*)d_in[5];
    const float* W_edge   = (const float*)d_in[6];
    const float* att_edge = (const float*)d_in[7];
    const float* bias_gat = (const float*)d_in[8];
    const float* W1       = (const float*)d_in[9];
    const float* b1       = (const float*)d_in[10];
    const float* prelu_a  = (const float*)d_in[11];
    const float* W2       = (const float*)d_in[12];
    const float* b2       = (const float*)d_in[13];
    float*       out      = (float*)d_out;

    char* base = (char*)d_ws;
    size_t off = 0;
    auto alloc = [&](size_t bytes) -> void* {
        void* p = base + off;
        off = (off + bytes + 255) & ~(size_t)255;
        return p;
    };
    int*      cnt     = (int*)     alloc((size_t)N_NODES * 4);
    int*      rowptr  = (int*)     alloc((size_t)(N_NODES + 1) * 4);
    float*    v       = (float*)   alloc(32 * 4);
    float*    a_src   = (float*)   alloc((size_t)N_NODES * 4 * 4);
    float*    a_dst   = (float*)   alloc((size_t)N_NODES * 4 * 4);
    uint32_t* xp2     = (uint32_t*)alloc((size_t)N_NODES * 64 * 4);
    uint4*    csr     = (uint4*)   alloc((size_t)N_EDGES * 16);
    float*    h_buf   = (float*)   alloc((size_t)N_NODES * 128 * 4);
    uint16_t* hist    = (uint16_t*)alloc((size_t)NB_H * N_NODES * 2);

    k_pre <<<NB_PRE, 256, 0, stream>>>(x, W_gat, att_src, att_dst,
                                       W_edge, att_edge, xp2,
                                       (float4*)a_src, (float4*)a_dst, v);
    k_hist<<<NB_H, 256, 0, stream>>>(ei, hist);
    k_red <<<196, 256, 0, stream>>>(hist, cnt);
    k_scan<<<1, 1024, 0, stream>>>(cnt, rowptr);
    k_scatter<<<SC_FULL + 1, 256, 0, stream>>>(
        ei, edge_attr, v, rowptr, cnt, csr);
    k_gather<<<N_NODES / 2, 128, 0, stream>>>(
        rowptr, csr, xp2, a_src, a_dst, bias_gat, (float2*)h_buf);
    k_mlp <<<N_NODES / 16, 256, 0, stream>>>(h_buf, W1, b1, prelu_a, W2, b2, out);
}

// Round 14
// 459.835 us; speedup vs baseline: 1.1563x; 1.0274x over previous
//
#include <hip/hip_runtime.h>
#include <cstdint>

#define N_NODES 50000
#define N_EDGES 1600000
#define NH 4
#define CC 32
#define HC 128          // NH*CC
#define LAT 32
#define NEG_SLOPE 0.2f

// fused k_pre role split: [hist | xp | node | v]
#define NB_HIST 250                      // 250 x 6400-edge chunks
#define CH_E    6400
#define NB_XP   1563                     // xp: 8x256 uint32 per block (2048)
#define NB_NODE 25                       // node: 2048 nodes per block
#define NB_PRE  (NB_HIST + NB_XP + NB_NODE + 1)

// scatter: 4 consecutive edges/thread, no LDS; 1562 full blocks + 1 tail block
#define SC_FULL 1562                     // covers 1562*1024 = 1,599,488 edges

// ---------------- bf16 helpers (RNE pack, shift-unpack) ----------------
__device__ __forceinline__ float bflo(uint32_t u) {
    union { uint32_t i; float f; } c; c.i = u << 16; return c.f;
}
__device__ __forceinline__ float bfhi(uint32_t u) {
    union { uint32_t i; float f; } c; c.i = u & 0xFFFF0000u; return c.f;
}
__device__ __forceinline__ uint32_t f2bf(float f) {
    union { float f; uint32_t i; } c; c.f = f;
    return (c.i + 0x7FFFu + ((c.i >> 16) & 1u)) >> 16;
}
__device__ __forceinline__ uint32_t pack2(float a, float b) {
    return f2bf(a) | (f2bf(b) << 16);
}
__device__ __forceinline__ float bpermf(int byteIdx, float v) {
    return __int_as_float(__builtin_amdgcn_ds_bpermute(byteIdx, __float_as_int(v)));
}
// fp8 e4m3fn pack/unpack (ae only feeds the self-loop mean -> 6% rel err ok)
__device__ __forceinline__ uint32_t f2e4m3(float x) {
    uint32_t u = __float_as_uint(x);
    uint32_t s = u >> 31;
    uint32_t mag = u & 0x7fffffffu;
    mag += 0x7ffffu + ((mag >> 20) & 1u);       // RNE at bit 20
    uint32_t e = mag >> 23;
    if (e < 121u) return s << 7;                // underflow -> 0
    uint32_t code = ((e - 120u) << 3) | ((mag >> 20) & 7u);
    if (code > 0x7Eu) code = 0x7Eu;             // clamp to 448
    return (s << 7) | code;
}
__device__ __forceinline__ float e4m32f(uint32_t b) {
    uint32_t e = (b >> 3) & 15u;
    if (e == 0u) return 0.f;
    return __uint_as_float(((b >> 7) << 31) | ((e + 120u) << 23) | ((b & 7u) << 20));
}

// ---------------------------------------------------------------- kernels

// fused front end: [hist | xp | node | v] by blockIdx range
__global__ __launch_bounds__(256) void k_pre(const float* __restrict__ x,
                                             const int* __restrict__ ei,
                                             const float* __restrict__ W_gat,
                                             const float* __restrict__ att_src,
                                             const float* __restrict__ att_dst,
                                             const float* __restrict__ W_edge,
                                             const float* __restrict__ att_edge,
                                             uint16_t* __restrict__ hist,
                                             uint32_t* __restrict__ xp2,
                                             float4* __restrict__ a_src,
                                             float4* __restrict__ a_dst,
                                             float* __restrict__ v) {
    __shared__ uint32_t lh[12500];             // hist: 25000 uint16 bins/pass
    int bid = blockIdx.x, t = threadIdx.x;
    if (bid < NB_HIST) {
        // atomic-free degree histogram (uint16 pairs packed in uint32)
        int b = bid;
        int base = b * CH_E;
        uint32_t* orow = (uint32_t*)(hist + (size_t)b * N_NODES);
        #pragma unroll 1
        for (int p = 0; p < 2; ++p) {
            for (int i = t; i < 12500; i += 256) lh[i] = 0;
            __syncthreads();
            int lo = p * 25000;
            #pragma unroll 1
            for (int it = 0; it < CH_E / 256; ++it) {
                int dst = ei[N_EDGES + base + it * 256 + t];
                int r = dst - lo;
                if (r >= 0 && r < 25000)
                    atomicAdd(&lh[r >> 1], 1u << ((r & 1) * 16));
            }
            __syncthreads();
            for (int i = t; i < 12500; i += 256)
                orow[p * 12500 + i] = lh[i];
            __syncthreads();
        }
    } else if (bid < NB_HIST + NB_XP) {
        int base = (bid - NB_HIST) * 2048;
        #pragma unroll
        for (int i = 0; i < 8; ++i) {
            int k = base + i * 256 + t;
            if (k >= N_NODES * 64) break;
            int n = k >> 6, c = (k & 63) * 2;
            float x0 = x[n * 3 + 0], x1 = x[n * 3 + 1], x2 = x[n * 3 + 2];
            float a = x0 * W_gat[c]   + x1 * W_gat[128 + c]   + x2 * W_gat[256 + c];
            float b = x0 * W_gat[c+1] + x1 * W_gat[128 + c+1] + x2 * W_gat[256 + c+1];
            xp2[k] = pack2(a, b);
        }
    } else if (bid < NB_HIST + NB_XP + NB_NODE) {
        __shared__ float us[12], ud[12];
        if (t < 12) {
            int i = t >> 2, h = t & 3;
            float s = 0.f;
            #pragma unroll
            for (int c = 0; c < 32; ++c)
                s += W_gat[i * 128 + h * 32 + c] * att_src[h * 32 + c];
            us[t] = s;
        } else if (t < 24) {
            int q = t - 12; int i = q >> 2, h = q & 3;
            float s = 0.f;
            #pragma unroll
            for (int c = 0; c < 32; ++c)
                s += W_gat[i * 128 + h * 32 + c] * att_dst[h * 32 + c];
            ud[q] = s;
        }
        __syncthreads();
        int base = (bid - NB_HIST - NB_XP) * 2048;
        #pragma unroll 1
        for (int i = 0; i < 8; ++i) {
            int n = base + i * 256 + t;
            if (n >= N_NODES) break;
            float x0 = x[n * 3 + 0], x1 = x[n * 3 + 1], x2 = x[n * 3 + 2];
            float s[4], d[4];
            #pragma unroll
            for (int h = 0; h < 4; ++h) {
                s[h] = x0 * us[h] + x1 * us[4 + h] + x2 * us[8 + h];
                d[h] = x0 * ud[h] + x1 * ud[4 + h] + x2 * ud[8 + h];
            }
            a_src[n] = make_float4(s[0], s[1], s[2], s[3]);
            a_dst[n] = make_float4(d[0], d[1], d[2], d[3]);
        }
    } else {
        if (t < 28) {
            int d = t >> 2, h = t & 3;
            float s = 0.f;
            #pragma unroll
            for (int c = 0; c < 32; ++c)
                s += W_edge[d * 128 + h * 32 + c] * att_edge[h * 32 + c];
            v[t] = s;
        }
    }
}

// sum the 250 partial histograms per node -> cnt
__global__ __launch_bounds__(256) void k_red(const uint16_t* __restrict__ hist,
                                             int* __restrict__ cnt) {
    int i = blockIdx.x * 256 + threadIdx.x;
    if (i >= N_NODES) return;
    int run = 0;
    size_t off = i;
    #pragma unroll 1
    for (int b = 0; b < NB_HIST; ++b, off += N_NODES)
        run += hist[off];
    cnt[i] = run;
}

// single-block exclusive prefix sum over cnt -> rowptr[N+1]
__global__ __launch_bounds__(1024) void k_scan(const int* __restrict__ cnt,
                                               int* __restrict__ rowptr) {
    __shared__ int part[1024];
    int t = threadIdx.x;
    const int W = (N_NODES + 1023) / 1024;
    int lo = t * W, hi = min(lo + W, N_NODES);
    int s = 0;
    for (int i = lo; i < hi; ++i) s += cnt[i];
    part[t] = s;
    __syncthreads();
    for (int off = 1; off < 1024; off <<= 1) {
        int vv = (t >= off) ? part[t - off] : 0;
        __syncthreads();
        part[t] += vv;
        __syncthreads();
    }
    int run = part[t] - s;   // exclusive base
    for (int i = lo; i < hi; ++i) { rowptr[i] = run; run += cnt[i]; }
    if (t == 1023) rowptr[N_NODES] = part[1023];
}

// scatter v4: 4 consecutive edges/thread, no LDS (R13 structure — accepted
// at its ~91us memory-system ceiling). NEW: folds a_src[src] into the record
// (comb = ae + a_src, bf16x2x2) and carries raw ae as 4xfp8 in the pad word,
// so k_gather loses its per-edge dependent a_src load.
__global__ __launch_bounds__(256) void k_scatter(const int* __restrict__ ei,
                                                 const float* __restrict__ edge_attr,
                                                 const float* __restrict__ v,
                                                 const float4* __restrict__ a_src,
                                                 const int* __restrict__ rowptr,
                                                 int* __restrict__ cnt,
                                                 uint4* __restrict__ csr) {
    int t = threadIdx.x;
    float vsr[28];
    #pragma unroll
    for (int i = 0; i < 28; ++i) vsr[i] = v[i];   // uniform addr -> s_load

    if (blockIdx.x == SC_FULL) {
        // tail: 512 edges, 2 per thread, scalar guarded
        int e0 = SC_FULL * 1024;
        #pragma unroll
        for (int q = 0; q < 2; ++q) {
            int e = e0 + q * 256 + t;
            if (e >= N_EDGES) continue;
            int src = ei[e];
            int dst = ei[N_EDGES + e];
            float4 as4 = a_src[src];
            float asv[4] = {as4.x, as4.y, as4.z, as4.w};
            float aeo[4];
            uint32_t ae8 = 0;
            #pragma unroll
            for (int h = 0; h < 4; ++h) {
                float aeh = 0.f;
                #pragma unroll
                for (int d = 0; d < 7; ++d)
                    aeh += edge_attr[e * 7 + d] * vsr[d * 4 + h];
                ae8 |= f2e4m3(aeh) << (h * 8);
                aeo[h] = aeh + asv[h];
            }
            int c = atomicSub(&cnt[dst], 1);
            csr[rowptr[dst] + c - 1] =
                make_uint4(pack2(aeo[0], aeo[1]), pack2(aeo[2], aeo[3]),
                           (uint32_t)src, ae8);
        }
        return;
    }

    int e = blockIdx.x * 1024 + t * 4;            // 4 consecutive edges
    int4 s4 = *(const int4*)&ei[e];
    int4 d4 = *(const int4*)&ei[N_EDGES + e];
    int srcv[4] = {s4.x, s4.y, s4.z, s4.w};
    int dst[4]  = {d4.x, d4.y, d4.z, d4.w};

    int rp[4];
    #pragma unroll
    for (int q = 0; q < 4; ++q)
        rp[q] = rowptr[dst[q]];                   // independent of atomics

    float4 as4[4];
    #pragma unroll
    for (int q = 0; q < 4; ++q)
        as4[q] = a_src[srcv[q]];                  // L2-resident 800KB table

    // 28 contiguous floats = 7 aligned float4 loads
    const float4* ea4 = (const float4*)&edge_attr[e * 7];
    float ea[28];
    #pragma unroll
    for (int i = 0; i < 7; ++i) {
        float4 vv = ea4[i];
        ea[i * 4 + 0] = vv.x; ea[i * 4 + 1] = vv.y;
        ea[i * 4 + 2] = vv.z; ea[i * 4 + 3] = vv.w;
    }

    uint4 rec[4];
    #pragma unroll
    for (int q = 0; q < 4; ++q) {
        float asv[4] = {as4[q].x, as4[q].y, as4[q].z, as4[q].w};
        float comb[4];
        uint32_t ae8 = 0;
        #pragma unroll
        for (int h = 0; h < 4; ++h) {
            float aeh = 0.f;
            #pragma unroll
            for (int d = 0; d < 7; ++d) aeh += ea[q * 7 + d] * vsr[d * 4 + h];
            ae8 |= f2e4m3(aeh) << (h * 8);
            comb[h] = aeh + asv[h];
        }
        rec[q] = make_uint4(pack2(comb[0], comb[1]), pack2(comb[2], comb[3]),
                            (uint32_t)srcv[q], ae8);
    }

    int c[4];
    #pragma unroll
    for (int q = 0; q < 4; ++q)
        c[q] = atomicSub(&cnt[dst[q]], 1);        // 4 atomics in flight
    #pragma unroll
    for (int q = 0; q < 4; ++q)
        csr[rp[q] + c[q] - 1] = rec[q];
}

// 2 nodes per 128-thr block (one wave each), 2 channels/lane.
// Batch-16 lane-distributed scheme; per-edge a_src load ELIMINATED
// (comb = ae + a_src baked into the record; ae recovered from fp8 byte
// for the self-loop mean).
__global__ __launch_bounds__(128) void k_gather(const int* __restrict__ rowptr,
                                                const uint4* __restrict__ csr,
                                                const uint32_t* __restrict__ xp2,
                                                const float* __restrict__ a_src,
                                                const float* __restrict__ a_dst,
                                                const float* __restrict__ bias_gat,
                                                float2* __restrict__ h_buf) {
    int n = blockIdx.x * 2 + (threadIdx.x >> 6);
    int l = threadIdx.x & 63;     // lane 0..63; channels 2l, 2l+1
    int h = l >> 4;               // head
    int i16 = l & 15;             // edge slot within a 16-batch
    int hb = h * 64;              // bpermute byte base: lanes [h*16, h*16+16)
    int start = rowptr[n], end = rowptr[n + 1];
    int deg = end - start;

    float ad_n = a_dst[n * 4 + h];
    float as_n = a_src[n * 4 + h];

    float acc0 = 0.f, acc1 = 0.f, den = 0.f;
    float aeb = 0.f, aer = 0.f;

    int nb = deg >> 4;
    int p = start;
    for (int b = 0; b < nb; ++b, p += 16) {
        uint4 rec = csr[p + i16];          // 16 consecutive recs, coalesced
        uint32_t aw = (h < 2) ? rec.x : rec.y;
        float comb = (h & 1) ? bfhi(aw) : bflo(aw);   // ae + a_src[src]
        float ae = e4m32f((rec.w >> (h * 8)) & 0xffu);
        int srcv = (int)rec.z;
        float al = comb + ad_n;
        al = al > 0.f ? al : NEG_SLOPE * al;
        float w = __expf(al);              // one exp covers 16 edges
        aeb += ae;
        #pragma unroll
        for (int i = 0; i < 16; ++i) {
            int s = __builtin_amdgcn_readlane(srcv, i);       // SGPR src
            float wi = bpermf(hb + i * 4, w);                 // my head's w_i
            uint32_t xu = xp2[s * 64 + l];                    // coalesced 256B
            acc0 += wi * bflo(xu);
            acc1 += wi * bfhi(xu);
            den  += wi;
        }
    }
    // remainder: scalar path (all lanes, one edge at a time)
    for (; p < end; ++p) {
        uint4 rec = csr[p];
        uint32_t aw = (h < 2) ? rec.x : rec.y;
        float comb = (h & 1) ? bfhi(aw) : bflo(aw);
        float ae = e4m32f((rec.w >> (h * 8)) & 0xffu);
        int src = (int)rec.z;
        float al = comb + ad_n;
        al = al > 0.f ? al : NEG_SLOPE * al;
        float w = __expf(al);
        uint32_t xu = xp2[src * 64 + l];
        acc0 += w * bflo(xu);
        acc1 += w * bfhi(xu);
        den  += w;
        aer  += ae;
    }

    // aesum: reduce batch partials across the 16-lane head group, + remainder
    float aesum = aeb;
    aesum += __shfl_xor(aesum, 1);
    aesum += __shfl_xor(aesum, 2);
    aesum += __shfl_xor(aesum, 4);
    aesum += __shfl_xor(aesum, 8);
    aesum += aer;

    // self loop: edge_attr = mean of incoming aeh (linearity of the .v dot)
    float invd = (deg > 0) ? (1.0f / (float)deg) : 1.0f;
    float alS = as_n + ad_n + aesum * invd;
    alS = alS > 0.f ? alS : NEG_SLOPE * alS;
    float wS = __expf(alS);
    uint32_t xs = xp2[n * 64 + l];
    acc0 += wS * bflo(xs);
    acc1 += wS * bfhi(xs);
    den  += wS;

    float2 bia = ((const float2*)bias_gat)[l];
    float r = 1.0f / den;
    float o0 = acc0 * r + bia.x;
    float o1 = acc1 * r + bia.y;
    o0 = o0 > 0.f ? o0 : (__expf(o0) - 1.0f);   // ELU
    o1 = o1 > 0.f ? o1 : (__expf(o1) - 1.0f);
    h_buf[n * 64 + l] = make_float2(o0, o1);
}

// fused MLP v2: 16 rows per 256-thread block, float4 LDS reads,
// 8 accumulators/thread.
__global__ __launch_bounds__(256) void k_mlp(const float* __restrict__ h_buf,
                                             const float* __restrict__ W1,
                                             const float* __restrict__ b1,
                                             const float* __restrict__ prelu_a,
                                             const float* __restrict__ W2,
                                             const float* __restrict__ b2,
                                             float* __restrict__ out) {
    __shared__ float sh[16][128];
    __shared__ float sh1[16][128];
    int t = threadIdx.x;
    int nb = blockIdx.x * 16;
    const float4* hb4 = (const float4*)(h_buf + (size_t)nb * 128);
    float4* sh4 = (float4*)sh;
    sh4[t]       = hb4[t];           // rows 0..7
    sh4[t + 256] = hb4[t + 256];     // rows 8..15
    __syncthreads();
    int k = t & 127, g = t >> 7;     // g in {0,1}: rows g*8..g*8+7
    float acc[8];
    float bb = b1[k];
    #pragma unroll
    for (int r = 0; r < 8; ++r) acc[r] = bb;
    const float4* shg = (const float4*)&sh[g * 8][0];   // row r at shg[r*32+d4]
    #pragma unroll 4
    for (int d4 = 0; d4 < 32; ++d4) {
        float w0 = W1[(d4 * 4 + 0) * 128 + k];
        float w1 = W1[(d4 * 4 + 1) * 128 + k];
        float w2 = W1[(d4 * 4 + 2) * 128 + k];
        float w3 = W1[(d4 * 4 + 3) * 128 + k];
        #pragma unroll
        for (int r = 0; r < 8; ++r) {
            float4 hv = shg[r * 32 + d4];
            acc[r] += hv.x * w0 + hv.y * w1 + hv.z * w2 + hv.w * w3;
        }
    }
    float a = prelu_a[0];
    #pragma unroll
    for (int r = 0; r < 8; ++r) {
        float vv = acc[r];
        sh1[g * 8 + r][k] = vv > 0.f ? vv : a * vv;
    }
    __syncthreads();
    int j = t & 31, r2 = t >> 5;     // r2 in 0..7; handles rows r2 and r2+8
    float o0 = b2[j], o1 = b2[j];
    const float4* s1a = (const float4*)&sh1[r2][0];
    const float4* s1b = (const float4*)&sh1[r2 + 8][0];
    #pragma unroll 4
    for (int d4 = 0; d4 < 32; ++d4) {
        float w0 = W2[(d4 * 4 + 0) * 32 + j];
        float w1 = W2[(d4 * 4 + 1) * 32 + j];
        float w2 = W2[(d4 * 4 + 2) * 32 + j];
        float w3 = W2[(d4 * 4 + 3) * 32 + j];
        float4 h0 = s1a[d4], h1 = s1b[d4];
        o0 += h0.x * w0 + h0.y * w1 + h0.z * w2 + h0.w * w3;
        o1 += h1.x * w0 + h1.y * w1 + h1.z * w2 + h1.w * w3;
    }
    out[(nb + r2) * 32 + j]     = o0;
    out[(nb + r2 + 8) * 32 + j] = o1;
}

// ---------------------------------------------------------------- launch

extern "C" void kernel_launch(void* const* d_in, const int* in_sizes, int n_in,
                              void* d_out, int out_size, void* d_ws, size_t ws_size,
                              hipStream_t stream) {
    const float* x        = (const float*)d_in[0];
    const int*   ei       = (const int*)d_in[1];     // int32 per harness contract
    const float* edge_attr= (const float*)d_in[2];
    const float* W_gat    = (const float*)d_in[3];
    const float* att_src  = (const float*)d_in[4];
    const float* att_dst  = (const float*)d_in[5];
    const float* W_edge   = (const float*)d_in[6];
    const float* att_edge = (const float*)d_in[7];
    const float* bias_gat = (const float*)d_in[8];
    const float* W1       = (const float*)d_in[9];
    const float* b1       = (const float*)d_in[10];
    const float* prelu_a  = (const float*)d_in[11];
    const float* W2       = (const float*)d_in[12];
    const float* b2       = (const float*)d_in[13];
    float*       out      = (float*)d_out;

    char* base = (char*)d_ws;
    size_t off = 0;
    auto alloc = [&](size_t bytes) -> void* {
        void* p = base + off;
        off = (off + bytes + 255) & ~(size_t)255;
        return p;
    };
    int*      cnt     = (int*)     alloc((size_t)N_NODES * 4);
    int*      rowptr  = (int*)     alloc((size_t)(N_NODES + 1) * 4);
    float*    v       = (float*)   alloc(32 * 4);
    float*    a_src   = (float*)   alloc((size_t)N_NODES * 4 * 4);
    float*    a_dst   = (float*)   alloc((size_t)N_NODES * 4 * 4);
    uint32_t* xp2     = (uint32_t*)alloc((size_t)N_NODES * 64 * 4);
    uint4*    csr     = (uint4*)   alloc((size_t)N_EDGES * 16);
    float*    h_buf   = (float*)   alloc((size_t)N_NODES * 128 * 4);
    uint16_t* hist    = (uint16_t*)alloc((size_t)NB_HIST * N_NODES * 2);

    k_pre <<<NB_PRE, 256, 0, stream>>>(x, ei, W_gat, att_src, att_dst,
                                       W_edge, att_edge, hist, xp2,
                                       (float4*)a_src, (float4*)a_dst, v);
    k_red <<<196, 256, 0, stream>>>(hist, cnt);
    k_scan<<<1, 1024, 0, stream>>>(cnt, rowptr);
    k_scatter<<<SC_FULL + 1, 256, 0, stream>>>(
        ei, edge_attr, v, (const float4*)a_src, rowptr, cnt, csr);
    k_gather<<<N_NODES / 2, 128, 0, stream>>>(
        rowptr, csr, xp2, a_src, a_dst, bias_gat, (float2*)h_buf);
    k_mlp <<<N_NODES / 16, 256, 0, stream>>>(h_buf, W1, b1, prelu_a, W2, b2, out);
}